// Round 8
// baseline (8701.537 us; speedup 1.0000x reference)
//
#include <hip/hip_runtime.h>
#include <math.h>

// Problem constants (fixed by reference).
#define HIDDEN 1024
#define MEL    80
#define TSTEPS 1000
#define BATCH  64

// R8 geometry: 256 blocks x 256 threads (4 waves). Wave wv of block b owns
// hidden unit u = 4b+wv END-TO-END: 4 gate rows x 1024 columns. Lane l:
// gate r = l>>4, column chunk c = l&15 (64 cols). The entire step is
// wave-local after the poll: no __syncthreads, no cross-wave reduce, no
// block-level state. Exchange is agent-scope (MALL-resident, not HBM
// write-through like R7's system scope) packed {tag:32|float:32} atomics.
#define NBLK 256
#define TPB  256

typedef unsigned long long ull;

// v_exp_f32-based activations (abs err ~1e-6 << 8.3e-4 threshold).
__device__ __forceinline__ float sigm_f(float x) { return 1.0f / (1.0f + __expf(-x)); }
__device__ __forceinline__ float tanh_f(float x) { return 1.0f - 2.0f / (1.0f + __expf(2.0f * x)); }

// LDS skew: logical h index i -> physical i + 4*(i>>6). Chunk c (64 floats)
// starts at bank (68c)%32 = 4c%32: 16 chunks -> 2-way bank aliasing (free,
// m136) for both the strided b32 writes and the b128 broadcast reads.
#define HEXP 1088   // 1024 + 4*16

__global__ __launch_bounds__(TPB, 1) void tts_recur(
    const float* __restrict__ dec_Wih,   // [4096, 80]
    const float* __restrict__ dec_Whh,   // [4096, 1024]
    const float* __restrict__ dec_bih,   // [4096]
    const float* __restrict__ dec_bhh,   // [4096]
    const float* __restrict__ lin_W,     // [80, 1024]
    const float* __restrict__ lin_b,     // [80]
    float* __restrict__ h_hist,          // [TSTEPS, 1024] (for epilogue)
    ull* __restrict__ hbuf)              // [2, 1024] packed {tag:32|float:32}
{
    const int tid  = threadIdx.x;
    const int wv   = tid >> 6;           // 0..3: unit within block
    const int lane = tid & 63;
    const int gate = lane >> 4;          // i,f,g,o row
    const int c    = lane & 15;          // 64-column chunk
    const int u    = blockIdx.x * 4 + wv;        // global hidden unit 0..1023
    const int row_g = gate * HIDDEN + u;         // global gate row

    __shared__ __align__(16) float hEx[4][HEXP]; // per-wave h tile (wave-private)

    // ---- one-time fold: w = Whh_row_slice + Wih_row @ lin_W_slice (regs) ----
    const float* wih = dec_Wih + (size_t)row_g * MEL;
    const float* whh = dec_Whh + (size_t)row_g * HIDDEN + c * 64;
    float4 w[16];
#pragma unroll
    for (int k = 0; k < 16; ++k)
        w[k] = *(const float4*)(whh + k * 4);
#pragma unroll 1
    for (int m = 0; m < MEL; ++m) {
        const float aw = wih[m];
        const float4* lw4 = (const float4*)(lin_W + (size_t)m * HIDDEN + c * 64);
#pragma unroll
        for (int k = 0; k < 8; ++k) {
            const float4 lw = lw4[k];
            w[k].x = fmaf(aw, lw.x, w[k].x); w[k].y = fmaf(aw, lw.y, w[k].y);
            w[k].z = fmaf(aw, lw.z, w[k].z); w[k].w = fmaf(aw, lw.w, w[k].w);
        }
#pragma unroll
        for (int k = 8; k < 16; ++k) {
            const float4 lw = lw4[k];
            w[k].x = fmaf(aw, lw.x, w[k].x); w[k].y = fmaf(aw, lw.y, w[k].y);
            w[k].z = fmaf(aw, lw.z, w[k].z); w[k].w = fmaf(aw, lw.w, w[k].w);
        }
    }
    float b_comb_r = dec_bih[row_g] + dec_bhh[row_g];
    const float b_dec_r = b_comb_r;                  // step 0 (x=0, no lin_b fold)
    for (int m = 0; m < MEL; ++m)
        b_comb_r = fmaf(wih[m], lin_b[m], b_comb_r);

    float c_prev = 0.0f;                             // replicated across all 64 lanes

    // ---- step 0: g = b_dec (h=c=x=0); standard gate path with c_prev=0 ----
    {
        const float g = b_dec_r;
        const float gi = __shfl(g, c, 64);
        const float gf = __shfl(g, 16 + c, 64);
        const float gg = __shfl(g, 32 + c, 64);
        const float go = __shfl(g, 48 + c, 64);
        const float cc = sigm_f(gf) * c_prev + sigm_f(gi) * tanh_f(gg);
        const float h  = sigm_f(go) * tanh_f(cc);
        c_prev = cc;
        if (lane == 0) {
            const ull pk = ((ull)1u << 32) | (ull)__float_as_uint(h);
            __hip_atomic_store(hbuf + u, pk,
                               __ATOMIC_RELAXED, __HIP_MEMORY_SCOPE_AGENT);
            h_hist[u] = h;
        }
    }

    // ---- steps 1..TSTEPS-1 (fully wave-autonomous) ----
    for (int t = 1; t < TSTEPS; ++t) {
        const unsigned tag = (unsigned)t;
        // Poll ALL 1024 slots of h[t-1]: 16 coalesced 8B agent-atomic loads
        // per lane (slot lane+64j), issued in parallel; retry only misses.
        {
            const ull* src = hbuf + ((t - 1) & 1) * HIDDEN;
            ull v[16];
#pragma unroll
            for (int j = 0; j < 16; ++j)
                v[j] = __hip_atomic_load(src + lane + 64 * j,
                                         __ATOMIC_RELAXED, __HIP_MEMORY_SCOPE_AGENT);
#pragma unroll
            for (int j = 0; j < 16; ++j) {
                while ((unsigned)(v[j] >> 32) != tag)
                    v[j] = __hip_atomic_load(src + lane + 64 * j,
                                             __ATOMIC_RELAXED, __HIP_MEMORY_SCOPE_AGENT);
                hEx[wv][lane + 68 * j] = __uint_as_float((unsigned)v[j]);
            }
        }
        // Per-wave DS ordering is HW-guaranteed; stop compiler reordering only.
        __builtin_amdgcn_wave_barrier();

        // MAC over own 64-col chunk: 16 x ds_read_b128 (2-way aliased = free,
        // 4-lane broadcast groups) + 64 fma into 4 accumulators.
        const float4* hp = (const float4*)(&hEx[wv][68 * c]);
        float a0 = 0.f, a1 = 0.f, a2 = 0.f, a3 = 0.f;
#pragma unroll
        for (int k = 0; k < 16; k += 4) {
            const float4 h0 = hp[k], h1 = hp[k + 1], h2 = hp[k + 2], h3 = hp[k + 3];
            a0 = fmaf(w[k].x, h0.x, a0);   a0 = fmaf(w[k].y, h0.y, a0);
            a0 = fmaf(w[k].z, h0.z, a0);   a0 = fmaf(w[k].w, h0.w, a0);
            a1 = fmaf(w[k+1].x, h1.x, a1); a1 = fmaf(w[k+1].y, h1.y, a1);
            a1 = fmaf(w[k+1].z, h1.z, a1); a1 = fmaf(w[k+1].w, h1.w, a1);
            a2 = fmaf(w[k+2].x, h2.x, a2); a2 = fmaf(w[k+2].y, h2.y, a2);
            a2 = fmaf(w[k+2].z, h2.z, a2); a2 = fmaf(w[k+2].w, h2.w, a2);
            a3 = fmaf(w[k+3].x, h3.x, a3); a3 = fmaf(w[k+3].y, h3.y, a3);
            a3 = fmaf(w[k+3].z, h3.z, a3); a3 = fmaf(w[k+3].w, h3.w, a3);
        }
        float acc = (a0 + a1) + (a2 + a3);
        // Reduce within each 16-lane gate group (xor<16 stays in-group).
        acc += __shfl_xor(acc, 1, 64);
        acc += __shfl_xor(acc, 2, 64);
        acc += __shfl_xor(acc, 4, 64);
        acc += __shfl_xor(acc, 8, 64);
        const float g = acc + b_comb_r;
        // Gate gather: lanes {c, 16+c, 32+c, 48+c} hold i,f,g,o row sums.
        const float gi = __shfl(g, c, 64);
        const float gf = __shfl(g, 16 + c, 64);
        const float gg = __shfl(g, 32 + c, 64);
        const float go = __shfl(g, 48 + c, 64);
        const float cc = sigm_f(gf) * c_prev + sigm_f(gi) * tanh_f(gg);
        const float h  = sigm_f(go) * tanh_f(cc);
        c_prev = cc;

        // Publish: lane 0's h data-depends (via shuffles) on EVERY lane's poll
        // loads -> publish(t) happens-after full consumption of h(t-2) ->
        // double-buffer overwrite is race-free (R4 proof, now per-wave).
        if (lane == 0) {
            const ull pk = ((ull)(unsigned)(t + 1) << 32) | (ull)__float_as_uint(h);
            __hip_atomic_store(hbuf + (t & 1) * HIDDEN + u, pk,
                               __ATOMIC_RELAXED, __HIP_MEMORY_SCOPE_AGENT);
            h_hist[(size_t)t * HIDDEN + u] = h;
        }
    }
}

// Epilogue: frame[t] = lin_W @ h[t] + lin_b, broadcast to 64 batch rows.
__global__ __launch_bounds__(128) void tts_frames(
    const float* __restrict__ lin_W, const float* __restrict__ lin_b,
    const float* __restrict__ h_hist, float* __restrict__ out)
{
    const int t = blockIdx.x;
    const int tid = threadIdx.x;
    __shared__ __align__(16) float h_sh[HIDDEN];
    __shared__ float f_s[MEL];
    const float4* src = (const float4*)(h_hist + (size_t)t * HIDDEN);
    ((float4*)h_sh)[tid] = src[tid];
    ((float4*)h_sh)[tid + 128] = src[tid + 128];
    __syncthreads();
    if (tid < MEL) {
        const float* wrow = lin_W + (size_t)tid * HIDDEN;
        float acc = lin_b[tid];
#pragma unroll 8
        for (int cc = 0; cc < HIDDEN; ++cc)
            acc = fmaf(wrow[cc], h_sh[cc], acc);
        f_s[tid] = acc;
    }
    __syncthreads();
    for (int idx = tid; idx < BATCH * MEL; idx += 128) {
        const int b = idx / MEL;
        const int m = idx - b * MEL;
        out[(size_t)b * TSTEPS * MEL + (size_t)t * MEL + m] = f_s[m];
    }
}

extern "C" void kernel_launch(void* const* d_in, const int* in_sizes, int n_in,
                              void* d_out, int out_size, void* d_ws, size_t ws_size,
                              hipStream_t stream) {
    // Inputs: 0 text, 1 text_lens, 2 max_audio_len, 3 W_emb, 4..7 enc_*,
    // 8..11 dec_{Wih,Whh,bih,bhh}, 12 lin_W, 13 lin_b. Encoder is dead code.
    const float* dec_Wih = (const float*)d_in[8];
    const float* dec_Whh = (const float*)d_in[9];
    const float* dec_bih = (const float*)d_in[10];
    const float* dec_bhh = (const float*)d_in[11];
    const float* lin_W   = (const float*)d_in[12];
    const float* lin_b   = (const float*)d_in[13];
    float* out = (float*)d_out;

    // Workspace: h_hist fp32 [1000][1024] (4,096,000 B) + hbuf [2][1024] ull.
    // 0xAA poison -> tag 0xAAAAAAAA never matches 1..1000, so no init pass.
    float* h_hist = (float*)d_ws;
    ull* hbuf = (ull*)((char*)d_ws + (size_t)TSTEPS * HIDDEN * sizeof(float));

    hipLaunchKernelGGL(tts_recur, dim3(NBLK), dim3(TPB), 0, stream,
                       dec_Wih, dec_Whh, dec_bih, dec_bhh, lin_W, lin_b, h_hist, hbuf);
    hipLaunchKernelGGL(tts_frames, dim3(TSTEPS), dim3(128), 0, stream,
                       lin_W, lin_b, h_hist, out);
}

// Round 9
// 2468.000 us; speedup vs baseline: 3.5257x; 3.5257x over previous
//
#include <hip/hip_runtime.h>
#include <math.h>

// Problem constants (fixed by reference).
#define HIDDEN 1024
#define MEL    80
#define TSTEPS 1000
#define BATCH  64

// R9 = R7 worker structure (best known: 2.12 us/step), byte-identical worker
// path, PLUS 192 burner blocks that spin dense FMA on the idle 192 CUs.
// Theory under test: the kernel is ~95% stall -> DVFS parks the clock near
// idle (~1 GHz), inflating the MALL exchange RTT ~2.4x. Burners raise
// utilization/power so the governor boosts core+fabric clocks.
#define NBLK 64     // worker blocks
#define NTOT 256    // workers + 192 burners (1 block/CU at 16 waves)
#define TPB  1024

typedef unsigned long long ull;

// v_exp_f32-based activations (abs err ~1e-6 << 8.3e-4 threshold).
__device__ __forceinline__ float sigm_f(float x) { return 1.0f / (1.0f + __expf(-x)); }
__device__ __forceinline__ float tanh_f(float x) { return 1.0f - 2.0f / (1.0f + __expf(2.0f * x)); }

__global__ __launch_bounds__(TPB, 4) void tts_recur(
    const float* __restrict__ dec_Wih,   // [4096, 80]
    const float* __restrict__ dec_Whh,   // [4096, 1024]
    const float* __restrict__ dec_bih,   // [4096]
    const float* __restrict__ dec_bhh,   // [4096]
    const float* __restrict__ lin_W,     // [80, 1024]
    const float* __restrict__ lin_b,     // [80]
    float* __restrict__ h_hist,          // [TSTEPS, 1024] (for epilogue)
    ull* __restrict__ hbuf)              // [2, 1024] packed {tag:32|float:32}
{
    const int tid  = threadIdx.x;

    // ---------------- burner path: DVFS boost, no shared state ----------------
    if (blockIdx.x >= NBLK) {
        const ull* watch = hbuf + HIDDEN;        // unit 0, odd buffer: final tag 1000
        float f0 = 1.0f, f1 = 1.1f, f2 = 1.2f, f3 = 1.3f,
              f4 = 1.4f, f5 = 1.5f, f6 = 1.6f, f7 = 1.7f;
        for (int it = 0; it < 6000000; ++it) {   // hard bound ~0.1-0.2 s
#pragma unroll
            for (int j = 0; j < 8; ++j) {        // 64 fma, 8 independent chains
                f0 = fmaf(f0, 1.0000001f, 1e-9f); f1 = fmaf(f1, 1.0000001f, 1e-9f);
                f2 = fmaf(f2, 1.0000001f, 1e-9f); f3 = fmaf(f3, 1.0000001f, 1e-9f);
                f4 = fmaf(f4, 1.0000001f, 1e-9f); f5 = fmaf(f5, 1.0000001f, 1e-9f);
                f6 = fmaf(f6, 1.0000001f, 1e-9f); f7 = fmaf(f7, 1.0000001f, 1e-9f);
            }
            if ((it & 1023) == 0) {              // ~every 15-30 us
                ull v = __hip_atomic_load(watch, __ATOMIC_RELAXED, __HIP_MEMORY_SCOPE_AGENT);
                if ((unsigned)(v >> 32) == (unsigned)TSTEPS) break;  // ==1000; poison!=1000
            }
        }
        // Keep the FMA chains alive (all f_i > 0 always -> never stores).
        if (f0 + f1 + f2 + f3 + f4 + f5 + f6 + f7 == -1.0f) h_hist[0] = f0;
        return;
    }

    // ---------------- worker path: R7 verbatim ----------------
    const int blk  = blockIdx.x;
    const int wv   = tid >> 6;           // 0..15: column slice / slot chunk
    const int lane = tid & 63;           // gate row (MAC) / column (poll)
    const int jj   = lane & 15;          // unit within block
    const int gate = lane >> 4;          // i,f,g,o
    const int unit_g = blk * 16 + jj;
    const int row_g  = gate * HIDDEN + unit_g;

    if (wv == 0) __builtin_amdgcn_s_setprio(3);

    __shared__ __align__(16) float hEx[16][64];   // per-wave h slice (wave-private)
    __shared__ float part[2][64 * 17];            // partials, pitch 17 (2-way = free)

    // ---- one-time fold: w = Whh_row_slice + Wih_row @ lin_W_slice (regs) ----
    const float* wih = dec_Wih + (size_t)row_g * MEL;
    const float* whh = dec_Whh + (size_t)row_g * HIDDEN + wv * 64;
    float4 w[16];
#pragma unroll
    for (int k = 0; k < 16; ++k)
        w[k] = *(const float4*)(whh + k * 4);
#pragma unroll 1
    for (int m = 0; m < MEL; ++m) {
        const float aw = wih[m];
        const float4* lw4 = (const float4*)(lin_W + (size_t)m * HIDDEN + wv * 64);
#pragma unroll
        for (int k = 0; k < 8; ++k) {
            const float4 lw = lw4[k];
            w[k].x = fmaf(aw, lw.x, w[k].x); w[k].y = fmaf(aw, lw.y, w[k].y);
            w[k].z = fmaf(aw, lw.z, w[k].z); w[k].w = fmaf(aw, lw.w, w[k].w);
        }
#pragma unroll
        for (int k = 8; k < 16; ++k) {
            const float4 lw = lw4[k];
            w[k].x = fmaf(aw, lw.x, w[k].x); w[k].y = fmaf(aw, lw.y, w[k].y);
            w[k].z = fmaf(aw, lw.z, w[k].z); w[k].w = fmaf(aw, lw.w, w[k].w);
        }
    }
    float b_comb_r = dec_bih[row_g] + dec_bhh[row_g];
    const float b_dec_r = b_comb_r;                  // step 0 (x=0, no lin_b fold)
    for (int m = 0; m < MEL; ++m)
        b_comb_r = fmaf(wih[m], lin_b[m], b_comb_r);

    float c_prev = 0.0f;                             // live on wave 0 lanes

    // ---- step 0: g = b_dec (h=c=x=0); wave 0 only ----
    if (wv == 0) {
        const float g = b_dec_r;
        const float gi = __shfl(g, jj, 64);
        const float gg = __shfl(g, 32 + jj, 64);
        const float go = __shfl(g, 48 + jj, 64);
        const float c  = sigm_f(gi) * tanh_f(gg);    // f-gate * c0 = 0
        const float h  = sigm_f(go) * tanh_f(c);
        c_prev = c;
        if (lane < 16) {
            const ull pk = ((ull)1u << 32) | (ull)__float_as_uint(h);
            __hip_atomic_store(hbuf + unit_g, pk,
                               __ATOMIC_RELAXED, __HIP_MEMORY_SCOPE_SYSTEM);
            h_hist[unit_g] = h;
        }
    }

    // ---- steps 1..TSTEPS-1 ----
    for (int t = 1; t < TSTEPS; ++t) {
        const int buf = t & 1;
        // Poll own slot (tag==t valid); tag travels with value in one 8B atomic.
        {
            const ull* src = hbuf + ((t - 1) & 1) * HIDDEN;
            ull v = __hip_atomic_load(src + tid, __ATOMIC_RELAXED, __HIP_MEMORY_SCOPE_SYSTEM);
            while ((unsigned)(v >> 32) != (unsigned)t)
                v = __hip_atomic_load(src + tid, __ATOMIC_RELAXED, __HIP_MEMORY_SCOPE_SYSTEM);
            hEx[wv][lane] = __uint_as_float((unsigned)v);
        }
        __builtin_amdgcn_wave_barrier();   // per-wave DS order is HW-guaranteed

        // Broadcast MAC: 16 uniform-address ds_read_b128 + 64 fma, 4 accs.
        const float4* hp = (const float4*)&hEx[wv][0];
        float a0 = 0.f, a1 = 0.f, a2 = 0.f, a3 = 0.f;
#pragma unroll
        for (int k = 0; k < 16; k += 4) {
            const float4 h0 = hp[k], h1 = hp[k + 1], h2 = hp[k + 2], h3 = hp[k + 3];
            a0 = fmaf(w[k].x, h0.x, a0);   a0 = fmaf(w[k].y, h0.y, a0);
            a0 = fmaf(w[k].z, h0.z, a0);   a0 = fmaf(w[k].w, h0.w, a0);
            a1 = fmaf(w[k+1].x, h1.x, a1); a1 = fmaf(w[k+1].y, h1.y, a1);
            a1 = fmaf(w[k+1].z, h1.z, a1); a1 = fmaf(w[k+1].w, h1.w, a1);
            a2 = fmaf(w[k+2].x, h2.x, a2); a2 = fmaf(w[k+2].y, h2.y, a2);
            a2 = fmaf(w[k+2].z, h2.z, a2); a2 = fmaf(w[k+2].w, h2.w, a2);
            a3 = fmaf(w[k+3].x, h3.x, a3); a3 = fmaf(w[k+3].y, h3.y, a3);
            a3 = fmaf(w[k+3].z, h3.z, a3); a3 = fmaf(w[k+3].w, h3.w, a3);
        }
        part[buf][lane * 17 + wv] = (a0 + a1) + (a2 + a3);
        __syncthreads();                               // barrier B (one/step)

        if (wv == 0) {
            const float* pr = &part[buf][lane * 17];
            float p[16];
#pragma unroll
            for (int i = 0; i < 16; ++i) p[i] = pr[i];
            const float s = (((p[0]+p[1])+(p[2]+p[3])) + ((p[4]+p[5])+(p[6]+p[7])))
                          + (((p[8]+p[9])+(p[10]+p[11])) + ((p[12]+p[13])+(p[14]+p[15])));
            const float g = s + b_comb_r;
            const float gi = __shfl(g, jj, 64);
            const float gf = __shfl(g, 16 + jj, 64);
            const float gg = __shfl(g, 32 + jj, 64);
            const float go = __shfl(g, 48 + jj, 64);
            const float c  = sigm_f(gf) * c_prev + sigm_f(gi) * tanh_f(gg);
            const float h  = sigm_f(go) * tanh_f(c);
            c_prev = c;
            if (lane < 16) {
                const ull pk = ((ull)(unsigned)(t + 1) << 32) | (ull)__float_as_uint(h);
                __hip_atomic_store(hbuf + buf * HIDDEN + unit_g, pk,
                                   __ATOMIC_RELAXED, __HIP_MEMORY_SCOPE_SYSTEM);
                h_hist[(size_t)t * HIDDEN + unit_g] = h;
            }
        }
        // Race-freedom + hbuf overwrite proofs: see R7 notes (unchanged).
    }
}

// Epilogue: frame[t] = lin_W @ h[t] + lin_b, broadcast to 64 batch rows.
__global__ __launch_bounds__(128) void tts_frames(
    const float* __restrict__ lin_W, const float* __restrict__ lin_b,
    const float* __restrict__ h_hist, float* __restrict__ out)
{
    const int t = blockIdx.x;
    const int tid = threadIdx.x;
    __shared__ __align__(16) float h_sh[HIDDEN];
    __shared__ float f_s[MEL];
    const float4* src = (const float4*)(h_hist + (size_t)t * HIDDEN);
    ((float4*)h_sh)[tid] = src[tid];
    ((float4*)h_sh)[tid + 128] = src[tid + 128];
    __syncthreads();
    if (tid < MEL) {
        const float* wrow = lin_W + (size_t)tid * HIDDEN;
        float acc = lin_b[tid];
#pragma unroll 8
        for (int cc = 0; cc < HIDDEN; ++cc)
            acc = fmaf(wrow[cc], h_sh[cc], acc);
        f_s[tid] = acc;
    }
    __syncthreads();
    for (int idx = tid; idx < BATCH * MEL; idx += 128) {
        const int b = idx / MEL;
        const int m = idx - b * MEL;
        out[(size_t)b * TSTEPS * MEL + (size_t)t * MEL + m] = f_s[m];
    }
}

extern "C" void kernel_launch(void* const* d_in, const int* in_sizes, int n_in,
                              void* d_out, int out_size, void* d_ws, size_t ws_size,
                              hipStream_t stream) {
    // Inputs: 0 text, 1 text_lens, 2 max_audio_len, 3 W_emb, 4..7 enc_*,
    // 8..11 dec_{Wih,Whh,bih,bhh}, 12 lin_W, 13 lin_b. Encoder is dead code.
    const float* dec_Wih = (const float*)d_in[8];
    const float* dec_Whh = (const float*)d_in[9];
    const float* dec_bih = (const float*)d_in[10];
    const float* dec_bhh = (const float*)d_in[11];
    const float* lin_W   = (const float*)d_in[12];
    const float* lin_b   = (const float*)d_in[13];
    float* out = (float*)d_out;

    // Workspace: h_hist fp32 [1000][1024] (4,096,000 B) + hbuf [2][1024] ull.
    // 0xAA poison -> tag 0xAAAAAAAA never matches 1..1000 (nor ==1000 for the
    // burner exit check), so no init pass needed.
    float* h_hist = (float*)d_ws;
    ull* hbuf = (ull*)((char*)d_ws + (size_t)TSTEPS * HIDDEN * sizeof(float));

    hipLaunchKernelGGL(tts_recur, dim3(NTOT), dim3(TPB), 0, stream,
                       dec_Wih, dec_Whh, dec_bih, dec_bhh, lin_W, lin_b, h_hist, hbuf);
    hipLaunchKernelGGL(tts_frames, dim3(TSTEPS), dim3(128), 0, stream,
                       lin_W, lin_b, h_hist, out);
}